// Round 1
// 368.199 us; speedup vs baseline: 1.5266x; 1.5266x over previous
//
#include <hip/hip_runtime.h>
#include <hip/hip_bf16.h>

#define BB 16
#define CC 384
#define HH 56
#define WW 56
#define PLANE (HH*WW)
#define NHW (BB*PLANE)

typedef __attribute__((ext_vector_type(8)))  short short8;   // 8 bf16 (4 VGPR) MFMA frag
typedef __attribute__((ext_vector_type(16))) float f32x16;   // 32x32 MFMA accumulator

// ---------------- Kernel 1: 31x31 depthwise conv via MFMA (+5x5 stats) ----------------
// Formulation: per ky, out-tile[m][n] += A(in rows y0+ky-15+m, cols x0-15+k) x T_ky,
//   T_ky[k][n] = w[ky][k-n] (Toeplitz band), K = 64 = 4 x mfma_f32_32x32x16_bf16.
// Accumulate over all 31 ky in AGPRs (out-stationary). Weights split hi+lo bf16
// (two MFMAs, shared A-frag) so only x-quantization error remains (~1e-3, below the
// existing yL bf16 rounding).
// Block = 4 waves = 4 batch-planes of one channel. Tiles y0,x0 in {0,24}: 24+32=56
// exact; overlap rows recompute identically (benign), stats masked.
// LDS plane stride 92 el: 184 B = 46 words == 14 mod 32 -> 2-way (free) on the
// 32-row ds_read_b64 A-frag reads; 184 % 8 == 0 keeps b64 alignment.
#define PSTR 92
#define PROWS 86               // rows -15..70 (15 zero halo each side)
#define PSZ (PROWS*PSTR)       // 7912 shorts per plane
#define WL_W 100               // shorts per (ky,h) padded weight row, idx = widx+32
#define WS_W 80                // shorts per ky2 padded small-weight row

static __device__ __forceinline__ short f2bf(float f) {
    // RNE float->bf16 (finite inputs only)
    unsigned int u = __float_as_uint(f);
    unsigned int r = (u + 0x7fffu + ((u >> 16) & 1u)) >> 16;
    return (short)r;
}

static __device__ __forceinline__ short8 ldA(const short* ap) {
    // 8 contiguous bf16, 8B-aligned by construction -> 2x ds_read_b64
    union { unsigned int u[4]; short8 v; } r;
    uint2 lo = *(const uint2*)(ap);
    uint2 hi = *(const uint2*)(ap + 4);
    r.u[0] = lo.x; r.u[1] = lo.y; r.u[2] = hi.x; r.u[3] = hi.y;
    return r.v;
}

static __device__ __forceinline__ short8 ldW(const unsigned int* p, unsigned int sh) {
    // 8 bf16 at arbitrary even-element offset: 5 aligned dwords + v_alignbit (sh in {0,16})
    union { unsigned int u[4]; short8 v; } r;
    unsigned int a0 = p[0], a1 = p[1], a2 = p[2], a3 = p[3], a4 = p[4];
    r.u[0] = __builtin_amdgcn_alignbit(a1, a0, sh);
    r.u[1] = __builtin_amdgcn_alignbit(a2, a1, sh);
    r.u[2] = __builtin_amdgcn_alignbit(a3, a2, sh);
    r.u[3] = __builtin_amdgcn_alignbit(a4, a3, sh);
    return r.v;
}

__global__ __launch_bounds__(256, 2) void conv_large_k(
    const float* __restrict__ x, const float* __restrict__ wL,
    const float* __restrict__ wS,
    unsigned short* __restrict__ yL, float* __restrict__ stats)
{
    __shared__ __align__(16) short planes[4*PSZ];      // 63296 B
    __shared__ __align__(16) short wpL[31*2*WL_W];     // 12400 B (hi,lo bands)
    __shared__ __align__(16) short wpS[5*WS_W];        //   800 B   -> 76.5 KB total, 2 blk/CU

    const int bid  = blockIdx.x;
    const int c    = bid % CC;
    const int bg   = bid / CC;          // batch group 0..3
    const int tid  = threadIdx.x;
    const int w    = tid >> 6;          // wave = plane
    const int lane = tid & 63;
    const int m    = lane & 31;         // A-row / B-col / D-col lane field
    const int g    = lane >> 5;         // k-group

    // ---- wave-local zero + stage own plane (bf16, halo zeros) ----
    short* pl = planes + w*PSZ;
    {
        uint4 z = make_uint4(0,0,0,0);
        uint4* p4 = (uint4*)pl;
        #pragma unroll 1
        for (int i = lane; i < PSZ/8; i += 64) p4[i] = z;
    }
    const int b = bg*4 + w;
    const float* xp = x + ((size_t)b*CC + c)*PLANE;
    #pragma unroll 1
    for (int i = lane; i < PLANE; i += 64) {
        int r  = i / WW;
        int cc = i - r*WW;
        pl[(r + 15)*PSTR + cc + 15] = f2bf(xp[i]);
    }

    // ---- cooperative weight-band build (shared by 4 waves, same c) ----
    const float* wrow = wL + c*961;
    #pragma unroll 1
    for (int i = tid; i < 31*2*WL_W; i += 256) {
        int ky  = i / (2*WL_W);
        int rem = i - ky*(2*WL_W);
        int h   = rem / WL_W;           // 0 = hi, 1 = lo residual
        int j   = rem - h*WL_W;
        int widx = j - 32;
        float v = 0.f;
        if (widx >= 0 && widx < 31) {
            float wv = wrow[ky*31 + widx];
            if (h) {
                short hi = f2bf(wv);
                v = wv - __uint_as_float(((unsigned int)(unsigned short)hi) << 16);
            } else v = wv;
        }
        wpL[i] = f2bf(v);
    }
    const float* wrowS = wS + c*25;
    #pragma unroll 1
    for (int i = tid; i < 5*WS_W; i += 256) {
        int ky = i / WS_W;
        int j  = i - ky*WS_W;
        int widx = j - 32;
        float v = (widx >= 0 && widx < 5) ? wrowS[ky*5 + widx] : 0.f;
        wpS[i] = f2bf(v);
    }
    __syncthreads();

    // ---- per-lane bases ----
    const int toff = 8*g - m;                       // B-frag weight index base
    const int t32L = toff + 32;                     // >= 1
    const unsigned int shL = (unsigned int)(t32L & 1) * 16u;
    const unsigned int* wLd = (const unsigned int*)wpL + (t32L >> 1);
    const int t32S = toff + 31;                     // small conv: delta = -1
    const unsigned int shS = (unsigned int)(t32S & 1) * 16u;
    const unsigned int* wSd = (const unsigned int*)wpS + (t32S >> 1);
    const short* abase = pl + m*PSTR + 8*g;

    f32x16 acc[4] = {};                             // tiles (ty,tx), y0/x0 = 24*ty/tx

    // ---- main loop: 31 ky x 4 Ksteps x 4 tiles x (hi,lo) = 992 MFMA ----
    #pragma unroll 1
    for (int ky = 0; ky < 31; ++ky) {
        const unsigned int* wk = wLd + ky*WL_W;     // ky*100 dwords
        short8 BH[4], BL[4];
        #pragma unroll
        for (int s = 0; s < 4; ++s) {
            BH[s] = ldW(wk + 8*s, shL);
            BL[s] = ldW(wk + (WL_W/2) + 8*s, shL);
        }
        const short* ar = abase + ky*PSTR;
        #pragma unroll
        for (int s = 0; s < 4; ++s) {
            short8 A4[4];
            #pragma unroll
            for (int t = 0; t < 4; ++t) {
                const int ty = t >> 1, tx = t & 1;
                A4[t] = ldA(ar + ty*(24*PSTR) + tx*24 + 16*s);
            }
            #pragma unroll
            for (int t = 0; t < 4; ++t)
                acc[t] = __builtin_amdgcn_mfma_f32_32x32x16_bf16(A4[t], BH[s], acc[t], 0, 0, 0);
            #pragma unroll
            for (int t = 0; t < 4; ++t)
                acc[t] = __builtin_amdgcn_mfma_f32_32x32x16_bf16(A4[t], BL[s], acc[t], 0, 0, 0);
        }
    }

    // ---- epilogue: per tile {5x5 MFMA for stats, masked stats, yL store} ----
    float sL = 0.f, sL2 = 0.f, sS = 0.f, sS2 = 0.f;
    unsigned short* yout = yL + ((size_t)b*CC + c)*PLANE;

    #pragma unroll
    for (int t = 0; t < 4; ++t) {
        const int ty = t >> 1, tx = t & 1;
        // small conv (stats only; kernel 2 recomputes values in fp32):
        //   k = n + kx + 1 in [1,36] -> 3 Ksteps; A col base = x0 + 12 (8B-aligned)
        f32x16 aS_ = {};
        const short* asb = abase + (ty*24 + 13)*PSTR + tx*24 + 12;
        #pragma unroll
        for (int k2 = 0; k2 < 5; ++k2) {
            const unsigned int* wk2 = wSd + k2*(WS_W/2);
            const short* ar2 = asb + k2*PSTR;
            #pragma unroll
            for (int s = 0; s < 3; ++s) {
                short8 bs = ldW(wk2 + 8*s, shS);
                short8 av = ldA(ar2 + 16*s);
                aS_ = __builtin_amdgcn_mfma_f32_32x32x16_bf16(av, bs, aS_, 0, 0, 0);
            }
        }
        // stats masked so the 24/32 tile overlap isn't double counted:
        //   tx==1 -> only cols n>=8 ; ty==1 -> only rows>=8 (regs 4..15)
        const float cm = (tx == 0 || m >= 8) ? 1.f : 0.f;
        #pragma unroll
        for (int r = 0; r < 16; ++r) {
            float v = acc[t][r];
            if (ty == 0 || r >= 4) {
                sL  = fmaf(cm, v,  sL);
                sL2 = fmaf(cm, v*v, sL2);
                float v2 = aS_[r];
                sS  = fmaf(cm, v2,  sS);
                sS2 = fmaf(cm, v2*v2, sS2);
            }
            const int row = (r & 3) + 8*(r >> 2) + 4*g;   // C/D: col=lane&31, row=f(reg,lane>>5)
            yout[(ty*24 + row)*WW + tx*24 + m] = (unsigned short)f2bf(v);
        }
    }

    // ---- wave reduce + atomics (per wave = per plane) ----
    #pragma unroll
    for (int off = 32; off > 0; off >>= 1) {
        sL  += __shfl_down(sL,  off);
        sL2 += __shfl_down(sL2, off);
        sS  += __shfl_down(sS,  off);
        sS2 += __shfl_down(sS2, off);
    }
    if (lane == 0) {
        atomicAdd(&stats[c],        sL);
        atomicAdd(&stats[CC + c],   sL2);
        atomicAdd(&stats[2*CC + c], sS);
        atomicAdd(&stats[3*CC + c], sS2);
    }
}

// ---------------- Kernel 2: 5x5 conv (fp32) + BN coeffs + fused affine epilogue ----------------
#define ST3 61
__global__ __launch_bounds__(256) void fuse_small_k(
    const float* __restrict__ x, const float* __restrict__ wS,
    const unsigned short* __restrict__ yL, const float* __restrict__ stats,
    const float* __restrict__ gL, const float* __restrict__ bL,
    const float* __restrict__ gS, const float* __restrict__ bS,
    float* __restrict__ out)
{
    __shared__ float in_s[60 * ST3]; // 14640 B

    const int bid = blockIdx.x;
    const int c   = bid % CC;
    const int tid = threadIdx.x;
    const float* __restrict__ w2 = wS + c * 25;   // uniform -> s_loads

    for (int i = tid; i < 60 * ST3; i += 256) in_s[i] = 0.f;
    __syncthreads();

    const float4* xp4 = (const float4*)(x + (size_t)bid * PLANE);
    for (int t = tid; t < PLANE / 4; t += 256) {
        int r  = t / (WW / 4);
        int c4 = (t - r * (WW / 4)) * 4;
        float4 v = xp4[t];
        float* dst = &in_s[(r + 2) * ST3 + 2 + c4];
        dst[0] = v.x; dst[1] = v.y; dst[2] = v.z; dst[3] = v.w;
    }
    __syncthreads();

    const float inv_n = 1.0f / (float)NHW;
    float mL = stats[c]          * inv_n;
    float vL = stats[CC + c]     * inv_n - mL * mL;
    float aL = rsqrtf(vL + 1e-5f) * gL[c];
    float mS = stats[2*CC + c]   * inv_n;
    float vS = stats[3*CC + c]   * inv_n - mS * mS;
    float aS = rsqrtf(vS + 1e-5f) * gS[c];
    float cst = bL[c] + bS[c] - mL * aL - mS * aS;

    const unsigned short* yp = yL + (size_t)bid * PLANE;
    float* op = out + (size_t)bid * PLANE;

    // 4 outputs per iter: 9-float row segments shared across the 4 (4x fewer LDS reads),
    // ushort4 yL loads, float4 stores.
    #pragma unroll 1
    for (int t = tid; t < PLANE / 4; t += 256) {
        int r  = t / 14;
        int c4 = (t - r * 14) * 4;
        float o0 = 0.f, o1 = 0.f, o2 = 0.f, o3 = 0.f;
        #pragma unroll
        for (int ky = 0; ky < 5; ++ky) {
            const float* rp = &in_s[(r + ky) * ST3 + c4];
            float f[9];
            #pragma unroll
            for (int j = 0; j < 9; ++j) f[j] = rp[j];
            const float* wr = w2 + ky * 5;
            #pragma unroll
            for (int kx = 0; kx < 5; ++kx) {
                float wv = wr[kx];
                o0 = fmaf(f[kx + 0], wv, o0);
                o1 = fmaf(f[kx + 1], wv, o1);
                o2 = fmaf(f[kx + 2], wv, o2);
                o3 = fmaf(f[kx + 3], wv, o3);
            }
        }
        ushort4 yv = *(const ushort4*)(yp + 4 * t);
        float4 res;
        res.x = fmaf(aL, __uint_as_float(((unsigned int)yv.x) << 16), fmaf(aS, o0, cst));
        res.y = fmaf(aL, __uint_as_float(((unsigned int)yv.y) << 16), fmaf(aS, o1, cst));
        res.z = fmaf(aL, __uint_as_float(((unsigned int)yv.z) << 16), fmaf(aS, o2, cst));
        res.w = fmaf(aL, __uint_as_float(((unsigned int)yv.w) << 16), fmaf(aS, o3, cst));
        *(float4*)(op + 4 * t) = res;
    }
}

extern "C" void kernel_launch(void* const* d_in, const int* in_sizes, int n_in,
                              void* d_out, int out_size, void* d_ws, size_t ws_size,
                              hipStream_t stream) {
    const float* x  = (const float*)d_in[0];
    const float* wL = (const float*)d_in[1];
    const float* gL = (const float*)d_in[2];
    const float* bL = (const float*)d_in[3];
    const float* wS = (const float*)d_in[4];
    const float* gS = (const float*)d_in[5];
    const float* bS = (const float*)d_in[6];
    float* out = (float*)d_out;

    unsigned short* yLbuf = (unsigned short*)d_ws;
    const size_t yl_bytes = (size_t)BB * CC * PLANE * sizeof(unsigned short); // 38.5 MB
    float* stats = (float*)((char*)d_ws + yl_bytes);

    hipMemsetAsync(stats, 0, 4 * CC * sizeof(float), stream); // raw sums

    conv_large_k<<<4 * CC, 256, 0, stream>>>(x, wL, wS, yLbuf, stats);
    fuse_small_k<<<BB * CC, 256, 0, stream>>>(x, wS, yLbuf, stats, gL, bL, gS, bS, out);
}